// Round 18
// baseline (160.565 us; speedup 1.0000x reference)
//
#include <hip/hip_runtime.h>
#include <math.h>
#include <stdint.h>

#define NLEV 16
#define TBL 524288
#define TMASK (TBL - 1)
#define BLOCK 256
#define SPT 4            // samples per thread in encode
#define P1 2654435761u
#define P2 805459861u

#define NQ 4                     // pipeline quarters
#define QSAMP 65536              // samples per quarter (262144/4)
#define ENC_BLOCKS 1024          // encode blocks per quarter (16 lvl x 64 chunks)
#define MLP_BLOCKS 512           // mlp blocks per quarter (65536/128)

struct ResArr { float r[NLEV]; };

typedef __attribute__((ext_vector_type(4))) float f32x4;
typedef __attribute__((ext_vector_type(8))) short bf16x8;   // 8 bf16 = 4 VGPRs
struct __attribute__((packed, aligned(8))) f4wrap { f32x4 v; };

__device__ __forceinline__ float silu_f(float v) {
    return __fdividef(v, 1.0f + __expf(-v));
}

// fp32 -> bf16 bits (RNE)
__device__ __forceinline__ uint32_t f2bf(float f) {
    uint32_t u = __float_as_uint(f);
    return (u + 0x7FFFu + ((u >> 16) & 1u)) >> 16;
}
__device__ __forceinline__ float bf2f(uint32_t b) {
    return __uint_as_float(b << 16);
}
__device__ __forceinline__ void split_bf(float x, bf16x8& hi, bf16x8& lo, int e) {
    const uint32_t hb = f2bf(x);
    hi[e] = (short)hb;
    lo[e] = (short)f2bf(x - bf2f(hb));
}

// encode block -> (level, global chunk). Per XCD (bid&7): 88 full-level
// blocks (lvl 5-15) + 40 cheap (lvl 0-4); chunk quarter-local [0,64) then
// offset by q*64. Every (lvl,chunk) pair covered exactly once across q=0..3.
__device__ __forceinline__ void enc_map(int bid, int q, int& lvl, int& chunk) {
    const int xcd = bid & 7;
    const int j   = bid >> 3;               // 0..127
    if (j < 88) { const int F = xcd * 88 + j;        lvl = 5 + (F >> 6); chunk = F & 63; }
    else        { const int C = xcd * 40 + (j - 88); lvl = C >> 6;       chunk = C & 63; }
    chunk += q * 64;
}

// ---------------- encode body (r17-identical arithmetic) ----------------
// L2-request-throughput bound (~8.9 req/cyc/XCD, 56% of 16-channel L2):
// occupancy-insensitive (r5==r6), balance-insensitive (r17). CU pipes idle
// during encode -> overlap the MLP via the fused-role kernel below.
__device__ __forceinline__ void encode_body(const float* __restrict__ x,
                                            const float* __restrict__ emb,
                                            uint32_t* __restrict__ enc_ws,
                                            int nsamp, const ResArr& res,
                                            int lvl, int chunk)
{
    const int t  = threadIdx.x;
    const int s0 = chunk * (BLOCK * SPT) + t;
    const float rs = res.r[lvl];
    const float* tabf = emb + (size_t)lvl * TBL * 2;

    uint32_t i0[SPT][4];
    float w0[SPT], w1[SPT], w2[SPT];
    uint32_t bad = 0;

    #pragma unroll
    for (int p = 0; p < SPT; ++p) {
        const int s = s0 + p * BLOCK;
        const float xv0 = __builtin_nontemporal_load(&x[(size_t)s * 3 + 0]);
        const float xv1 = __builtin_nontemporal_load(&x[(size_t)s * 3 + 1]);
        const float xv2 = __builtin_nontemporal_load(&x[(size_t)s * 3 + 2]);
        const float g0 = (xv0 + 1.0f) * 0.5f * rs;
        const float g1 = (xv1 + 1.0f) * 0.5f * rs;
        const float g2 = (xv2 + 1.0f) * 0.5f * rs;
        const float f0 = floorf(g0), f1 = floorf(g1), f2 = floorf(g2);
        w0[p] = g0 - f0; w1[p] = g1 - f1; w2[p] = g2 - f2;
        const uint32_t hb = (uint32_t)f0 + (uint32_t)f1 * P1 + (uint32_t)f2 * P2;
        #pragma unroll
        for (int q = 0; q < 4; ++q) {
            uint32_t h = hb;
            if ((q >> 1) & 1) h += P1;
            if (q & 1)        h += P2;
            i0[p][q] = h & TMASK;
            bad |= (uint32_t)(i0[p][q] == TMASK);
        }
    }

    f32x4 v[SPT][4];
    if (__builtin_expect(__any((int)bad), 0)) {
        #pragma unroll
        for (int p = 0; p < SPT; ++p)
            #pragma unroll
            for (int q = 0; q < 4; ++q) {
                const uint32_t a = i0[p][q];
                const uint32_t b = (a + 1u) & TMASK;
                const float2 lo = *(const float2*)(tabf + 2 * (size_t)a);
                const float2 hi = *(const float2*)(tabf + 2 * (size_t)b);
                v[p][q] = f32x4{lo.x, lo.y, hi.x, hi.y};
            }
    } else {
        #pragma unroll
        for (int p = 0; p < SPT; ++p)
            #pragma unroll
            for (int q = 0; q < 4; ++q)
                v[p][q] = ((const f4wrap*)(tabf + 2 * (size_t)i0[p][q]))->v;
    }

    #pragma unroll
    for (int p = 0; p < SPT; ++p) {
        const float om0 = 1.0f - w0[p], om1 = 1.0f - w1[p], om2 = 1.0f - w2[p];
        float e0 = 0.0f, e1 = 0.0f;
        #pragma unroll
        for (int q = 0; q < 4; ++q) {
            float wb = (((q >> 1) & 1) ? w1[p] : om1) * ((q & 1) ? w2[p] : om2);
            const float c0 = om0 * wb;
            const float c1 = w0[p] * wb;
            e0 = fmaf(c0, v[p][q].x, fmaf(c1, v[p][q].z, e0));
            e1 = fmaf(c0, v[p][q].y, fmaf(c1, v[p][q].w, e1));
        }
        const int s = s0 + p * BLOCK;
        const uint32_t pk = f2bf(e0) | (f2bf(e1) << 16);
        __builtin_nontemporal_store(pk, &enc_ws[(size_t)lvl * nsamp + s]);
    }
}

// ---------------- MLP body (r16/r17-identical arithmetic, ~30us/full) ----------------
__device__ __forceinline__ void mlp_body(const uint32_t* __restrict__ enc_ws,
                                         const float* __restrict__ W1,
                                         const float* __restrict__ b1,
                                         const float* __restrict__ W2,
                                         const float* __restrict__ b2,
                                         const float* __restrict__ Wout,
                                         const float* __restrict__ bout,
                                         float* __restrict__ out, int nsamp,
                                         int sbase0, unsigned short* hbuf)
{
    const int tid  = threadIdx.x;
    const int wid  = tid >> 6;
    const int lane = tid & 63;
    const int l15  = lane & 15;
    const int g    = lane >> 4;
    const int sbase = sbase0 + wid * 32;
    unsigned short* hw = hbuf + wid * (32 * 72);

    bf16x8 b1hi[4], b1lo[4];
    float  b1v[4];
    #pragma unroll
    for (int n = 0; n < 4; ++n) {
        const float* wr = W1 + (n * 16 + l15) * 32 + g * 8;
        const f32x4 wv0 = ((const f4wrap*)wr)->v;
        const f32x4 wv1 = ((const f4wrap*)(wr + 4))->v;
        #pragma unroll
        for (int e = 0; e < 4; ++e) {
            split_bf(wv0[e], b1hi[n], b1lo[n], e);
            split_bf(wv1[e], b1hi[n], b1lo[n], e + 4);
        }
        b1v[n] = b1[n * 16 + l15];
    }

    #pragma unroll
    for (int m = 0; m < 2; ++m) {
        union { uint32_t u[4]; bf16x8 v; } af;
        const int s = sbase + m * 16 + l15;
        #pragma unroll
        for (int d = 0; d < 4; ++d)
            af.u[d] = enc_ws[(size_t)(g * 4 + d) * nsamp + s];
        #pragma unroll
        for (int n = 0; n < 4; ++n) {
            f32x4 acc = {0.f, 0.f, 0.f, 0.f};
            acc = __builtin_amdgcn_mfma_f32_16x16x32_bf16(af.v, b1lo[n], acc, 0, 0, 0);
            acc = __builtin_amdgcn_mfma_f32_16x16x32_bf16(af.v, b1hi[n], acc, 0, 0, 0);
            #pragma unroll
            for (int r = 0; r < 4; ++r) {
                const int row = m * 16 + g * 4 + r;
                const int col = n * 16 + l15;
                hw[row * 72 + col] = (unsigned short)f2bf(silu_f(acc[r] + b1v[n]));
            }
        }
    }

    f32x4 acc2[2][4];
    #pragma unroll
    for (int m = 0; m < 2; ++m)
        #pragma unroll
        for (int n = 0; n < 4; ++n)
            acc2[m][n] = f32x4{0.f, 0.f, 0.f, 0.f};

    #pragma unroll
    for (int ks = 0; ks < 2; ++ks) {
        bf16x8 b2hi[4], b2lo[4];
        #pragma unroll
        for (int n = 0; n < 4; ++n) {
            const float* wr = W2 + (n * 16 + l15) * 64 + ks * 32 + g * 8;
            const f32x4 wv0 = ((const f4wrap*)wr)->v;
            const f32x4 wv1 = ((const f4wrap*)(wr + 4))->v;
            #pragma unroll
            for (int e = 0; e < 4; ++e) {
                split_bf(wv0[e], b2hi[n], b2lo[n], e);
                split_bf(wv1[e], b2hi[n], b2lo[n], e + 4);
            }
        }
        #pragma unroll
        for (int m = 0; m < 2; ++m) {
            const bf16x8 a2 = *(const bf16x8*)&hw[(m * 16 + l15) * 72 + ks * 32 + g * 8];
            #pragma unroll
            for (int n = 0; n < 4; ++n) {
                acc2[m][n] = __builtin_amdgcn_mfma_f32_16x16x32_bf16(a2, b2lo[n], acc2[m][n], 0, 0, 0);
                acc2[m][n] = __builtin_amdgcn_mfma_f32_16x16x32_bf16(a2, b2hi[n], acc2[m][n], 0, 0, 0);
            }
        }
    }

    float b2v[4], wov[4];
    #pragma unroll
    for (int n = 0; n < 4; ++n) {
        b2v[n] = b2[n * 16 + l15];
        wov[n] = Wout[n * 16 + l15];
    }
    const float bo = bout[0];

    #pragma unroll
    for (int m = 0; m < 2; ++m) {
        float part[4] = {0.f, 0.f, 0.f, 0.f};
        #pragma unroll
        for (int n = 0; n < 4; ++n)
            #pragma unroll
            for (int r = 0; r < 4; ++r)
                part[r] += silu_f(acc2[m][n][r] + b2v[n]) * wov[n];
        #pragma unroll
        for (int mask = 1; mask <= 8; mask <<= 1)
            #pragma unroll
            for (int r = 0; r < 4; ++r)
                part[r] += __shfl_xor(part[r], mask, 64);
        if (l15 == 0) {
            #pragma unroll
            for (int r = 0; r < 4; ++r)
                out[sbase + m * 16 + g * 4 + r] = part[r] + bo;
        }
    }
}

// ---------------- Kernels ----------------
__global__ void __launch_bounds__(BLOCK)
encode_q_kernel(const float* __restrict__ x, const float* __restrict__ emb,
                uint32_t* __restrict__ enc_ws, int nsamp, ResArr res, int q)
{
    int lvl, chunk;
    enc_map(blockIdx.x, q, lvl, chunk);
    encode_body(x, emb, enc_ws, nsamp, res, lvl, chunk);
}

// Fused role kernel: blocks [0,ENC_BLOCKS) encode quarter qe; blocks
// [ENC_BLOCKS, ENC_BLOCKS+MLP_BLOCKS) run the MLP on quarter qm (written by
// the PREVIOUS dispatch -> stream order guarantees visibility). The two
// roles are independent: no cross-block sync. Encode (L2-gather-bound) and
// MLP (MFMA/DS/VALU-bound) co-resident -> MLP hides under encode.
__global__ void __launch_bounds__(BLOCK)
fused_q_kernel(const float* __restrict__ x, const float* __restrict__ emb,
               uint32_t* __restrict__ enc_ws,
               const float* __restrict__ W1, const float* __restrict__ b1,
               const float* __restrict__ W2, const float* __restrict__ b2,
               const float* __restrict__ Wout, const float* __restrict__ bout,
               float* __restrict__ out, int nsamp, ResArr res, int qe, int qm)
{
    __shared__ __align__(16) unsigned short hbuf[4 * 32 * 72];
    if (blockIdx.x < ENC_BLOCKS) {
        int lvl, chunk;
        enc_map(blockIdx.x, qe, lvl, chunk);
        encode_body(x, emb, enc_ws, nsamp, res, lvl, chunk);
    } else {
        const int mbid = blockIdx.x - ENC_BLOCKS;
        mlp_body(enc_ws, W1, b1, W2, b2, Wout, bout, out, nsamp,
                 qm * QSAMP + mbid * 128, hbuf);
    }
}

__global__ void __launch_bounds__(BLOCK)
mlp_q_kernel(const uint32_t* __restrict__ enc_ws,
             const float* __restrict__ W1, const float* __restrict__ b1,
             const float* __restrict__ W2, const float* __restrict__ b2,
             const float* __restrict__ Wout, const float* __restrict__ bout,
             float* __restrict__ out, int nsamp, int q)
{
    __shared__ __align__(16) unsigned short hbuf[4 * 32 * 72];
    mlp_body(enc_ws, W1, b1, W2, b2, Wout, bout, out, nsamp,
             q * QSAMP + blockIdx.x * 128, hbuf);
}

// ---------------- Fallback: monolithic (if ws too small) ----------------
__global__ void __launch_bounds__(BLOCK)
hashgrid_mlp_kernel(const float* __restrict__ x,
                    const float* __restrict__ emb,
                    const float* __restrict__ W1,
                    const float* __restrict__ b1,
                    const float* __restrict__ W2,
                    const float* __restrict__ b2,
                    const float* __restrict__ Wout,
                    const float* __restrict__ bout,
                    float* __restrict__ out,
                    ResArr res)
{
    const int t = threadIdx.x;
    const int s = blockIdx.x * BLOCK + t;

    const float xn0 = (x[(size_t)s * 3 + 0] + 1.0f) * 0.5f;
    const float xn1 = (x[(size_t)s * 3 + 1] + 1.0f) * 0.5f;
    const float xn2 = (x[(size_t)s * 3 + 2] + 1.0f) * 0.5f;

    float enc[2 * NLEV];
    #pragma unroll
    for (int l = 0; l < NLEV; ++l) {
        const float rs = res.r[l];
        const float g0 = xn0 * rs, g1 = xn1 * rs, g2 = xn2 * rs;
        const float f0 = floorf(g0), f1 = floorf(g1), f2 = floorf(g2);
        const float w0 = g0 - f0, w1 = g1 - f1, w2 = g2 - f2;
        const uint32_t hb = (uint32_t)f0 + (uint32_t)f1 * P1 + (uint32_t)f2 * P2;
        const float2* tab = (const float2*)emb + (size_t)l * TBL;
        const float om0 = 1.0f - w0, om1 = 1.0f - w1, om2 = 1.0f - w2;
        float e0 = 0.0f, e1 = 0.0f;
        #pragma unroll
        for (int c = 0; c < 8; ++c) {
            const uint32_t cb0 = (c >> 2) & 1, cb1 = (c >> 1) & 1, cb2 = c & 1;
            uint32_t h = hb;
            if (cb0) h += 1u;
            if (cb1) h += P1;
            if (cb2) h += P2;
            h &= TMASK;
            const float2 vv = tab[h];
            float wt = (cb0 ? w0 : om0) * (cb1 ? w1 : om1);
            wt *= (cb2 ? w2 : om2);
            e0 = fmaf(wt, vv.x, e0);
            e1 = fmaf(wt, vv.y, e1);
        }
        enc[2 * l + 0] = e0;
        enc[2 * l + 1] = e1;
    }

    float h1[64];
    #pragma unroll
    for (int i = 0; i < 64; ++i) {
        float acc = b1[i];
        #pragma unroll
        for (int k = 0; k < 32; ++k)
            acc = fmaf(enc[k], W1[i * 32 + k], acc);
        h1[i] = silu_f(acc);
    }
    float o = bout[0];
    #pragma unroll
    for (int i = 0; i < 64; ++i) {
        float acc = b2[i];
        #pragma unroll
        for (int k = 0; k < 64; ++k)
            acc = fmaf(h1[k], W2[i * 64 + k], acc);
        o = fmaf(silu_f(acc), Wout[i], o);
    }
    out[s] = o;
}

extern "C" void kernel_launch(void* const* d_in, const int* in_sizes, int n_in,
                              void* d_out, int out_size, void* d_ws, size_t ws_size,
                              hipStream_t stream) {
    const float* x    = (const float*)d_in[0];
    const float* emb  = (const float*)d_in[1];
    const float* W1   = (const float*)d_in[2];
    const float* b1   = (const float*)d_in[3];
    const float* W2   = (const float*)d_in[4];
    const float* b2   = (const float*)d_in[5];
    const float* Wout = (const float*)d_in[6];
    const float* bout = (const float*)d_in[7];
    float* out = (float*)d_out;

    ResArr res;
    const double lg0 = log(16.0), lg1 = log(2048.0);
    for (int i = 0; i < NLEV; ++i)
        res.r[i] = (float)exp(lg0 + (lg1 - lg0) * (double)i / 15.0);

    const int n = in_sizes[0] / 3;                     // 262144 samples
    const size_t ws_needed = (size_t)n * NLEV * sizeof(uint32_t);

    if (ws_size >= ws_needed && n == NQ * QSAMP) {
        uint32_t* enc_ws = (uint32_t*)d_ws;
        // software pipeline: enc(q0); [enc(q)||mlp(q-1)] x3; mlp(q3)
        encode_q_kernel<<<dim3(ENC_BLOCKS), BLOCK, 0, stream>>>(x, emb, enc_ws, n, res, 0);
        for (int q = 1; q < NQ; ++q)
            fused_q_kernel<<<dim3(ENC_BLOCKS + MLP_BLOCKS), BLOCK, 0, stream>>>(
                x, emb, enc_ws, W1, b1, W2, b2, Wout, bout, out, n, res, q, q - 1);
        mlp_q_kernel<<<dim3(MLP_BLOCKS), BLOCK, 0, stream>>>(
            enc_ws, W1, b1, W2, b2, Wout, bout, out, n, NQ - 1);
    } else {
        dim3 grid(n / BLOCK);
        hashgrid_mlp_kernel<<<grid, BLOCK, 0, stream>>>(x, emb, W1, b1, W2, b2,
                                                        Wout, bout, out, res);
    }
}

// Round 19
// 123.363 us; speedup vs baseline: 1.3016x; 1.3016x over previous
//
#include <hip/hip_runtime.h>
#include <math.h>
#include <stdint.h>

#define NLEV 16
#define TBL 524288
#define TMASK (TBL - 1)
#define BLOCK 256
#define SPT 4            // samples per thread in encode
#define P1 2654435761u
#define P2 805459861u

struct ResArr { float r[NLEV]; };

typedef __attribute__((ext_vector_type(4))) float f32x4;
typedef __attribute__((ext_vector_type(8))) short bf16x8;   // 8 bf16 = 4 VGPRs
struct __attribute__((packed, aligned(8))) f4wrap { f32x4 v; };

__device__ __forceinline__ float silu_f(float v) {
    return __fdividef(v, 1.0f + __expf(-v));
}

// fp32 -> bf16 bits (RNE)
__device__ __forceinline__ uint32_t f2bf(float f) {
    uint32_t u = __float_as_uint(f);
    return (u + 0x7FFFu + ((u >> 16) & 1u)) >> 16;
}
__device__ __forceinline__ float bf2f(uint32_t b) {
    return __uint_as_float(b << 16);
}
// split x = hi + lo (both bf16) for WEIGHT fragments (B-side keeps precision)
__device__ __forceinline__ void split_bf(float x, bf16x8& hi, bf16x8& lo, int e) {
    const uint32_t hb = f2bf(x);
    hi[e] = (short)hb;
    lo[e] = (short)f2bf(x - bf2f(hb));
}

// ---------------- Kernel A: hash-grid encode (r17 exact revert) ----------------
// Pinned ~98us by random-gather L2 request throughput (~8.9 req/cyc/XCD):
// occupancy-insensitive (r5==r6), balance-insensitive (r17), overlap-negative
// (r18: sample-quartering forced 4x slice re-warm, FETCH 86->280MB). This
// single-dispatch form keeps each XCD's slices resident for the whole pass.
__global__ void __launch_bounds__(BLOCK)
encode_kernel(const float* __restrict__ x,
              const float* __restrict__ emb,
              uint32_t* __restrict__ enc_ws,
              int nsamp, ResArr res)
{
    const int bid = blockIdx.x;
    const int xcd = bid & 7;
    const int j   = bid >> 3;                 // per-XCD local index 0..511
    int lvl, chunk;
    if (j < 352) {                            // full levels 5..15 (11 x 256 blocks)
        const int F = xcd * 352 + j;
        lvl = 5 + (F >> 8);
        chunk = F & 255;
    } else {                                  // cheap levels 0..4 (5 x 256 blocks)
        const int C = xcd * 160 + (j - 352);
        lvl = C >> 8;
        chunk = C & 255;
    }

    const int t  = threadIdx.x;
    const int s0 = chunk * (BLOCK * SPT) + t;
    const float rs = res.r[lvl];
    const float* tabf = emb + (size_t)lvl * TBL * 2;

    uint32_t i0[SPT][4];
    float w0[SPT], w1[SPT], w2[SPT];
    uint32_t bad = 0;

    #pragma unroll
    for (int p = 0; p < SPT; ++p) {
        const int s = s0 + p * BLOCK;
        const float xv0 = __builtin_nontemporal_load(&x[(size_t)s * 3 + 0]);
        const float xv1 = __builtin_nontemporal_load(&x[(size_t)s * 3 + 1]);
        const float xv2 = __builtin_nontemporal_load(&x[(size_t)s * 3 + 2]);
        const float g0 = (xv0 + 1.0f) * 0.5f * rs;
        const float g1 = (xv1 + 1.0f) * 0.5f * rs;
        const float g2 = (xv2 + 1.0f) * 0.5f * rs;
        const float f0 = floorf(g0), f1 = floorf(g1), f2 = floorf(g2);
        w0[p] = g0 - f0; w1[p] = g1 - f1; w2[p] = g2 - f2;
        const uint32_t hb = (uint32_t)f0 + (uint32_t)f1 * P1 + (uint32_t)f2 * P2;
        #pragma unroll
        for (int q = 0; q < 4; ++q) {
            uint32_t h = hb;
            if ((q >> 1) & 1) h += P1;
            if (q & 1)        h += P2;
            i0[p][q] = h & TMASK;
            bad |= (uint32_t)(i0[p][q] == TMASK);
        }
    }

    f32x4 v[SPT][4];
    if (__builtin_expect(__any((int)bad), 0)) {
        #pragma unroll
        for (int p = 0; p < SPT; ++p)
            #pragma unroll
            for (int q = 0; q < 4; ++q) {
                const uint32_t a = i0[p][q];
                const uint32_t b = (a + 1u) & TMASK;
                const float2 lo = *(const float2*)(tabf + 2 * (size_t)a);
                const float2 hi = *(const float2*)(tabf + 2 * (size_t)b);
                v[p][q] = f32x4{lo.x, lo.y, hi.x, hi.y};
            }
    } else {
        #pragma unroll
        for (int p = 0; p < SPT; ++p)
            #pragma unroll
            for (int q = 0; q < 4; ++q)
                v[p][q] = ((const f4wrap*)(tabf + 2 * (size_t)i0[p][q]))->v;
    }

    #pragma unroll
    for (int p = 0; p < SPT; ++p) {
        const float om0 = 1.0f - w0[p], om1 = 1.0f - w1[p], om2 = 1.0f - w2[p];
        float e0 = 0.0f, e1 = 0.0f;
        #pragma unroll
        for (int q = 0; q < 4; ++q) {
            float wb = (((q >> 1) & 1) ? w1[p] : om1) * ((q & 1) ? w2[p] : om2);
            const float c0 = om0 * wb;
            const float c1 = w0[p] * wb;
            e0 = fmaf(c0, v[p][q].x, fmaf(c1, v[p][q].z, e0));
            e1 = fmaf(c0, v[p][q].y, fmaf(c1, v[p][q].w, e1));
        }
        const int s = s0 + p * BLOCK;
        const uint32_t pk = f2bf(e0) | (f2bf(e1) << 16);
        __builtin_nontemporal_store(pk, &enc_ws[(size_t)lvl * nsamp + s]);
    }
}

// ---------------- Kernel B: MLP via bf16-A / split-bf16-B MFMA ----------------
// r17 arithmetic, but 4 M-tiles per wave (64 samples/wave, 256/block): the
// per-wave fixed overhead (weight-fragment loads + hi/lo split VALU) now
// amortizes over 2x the samples; MFMA count per sample unchanged. Per-sample
// arithmetic is bit-identical to r16/r17 -> absmax must stay 3.051758e-05.
// C/D layout (HW-verified): col = lane&15, row = (lane>>4)*4 + reg.
__global__ void __launch_bounds__(BLOCK)
mlp_mfma_kernel(const uint32_t* __restrict__ enc_ws,
                const float* __restrict__ W1,
                const float* __restrict__ b1,
                const float* __restrict__ W2,
                const float* __restrict__ b2,
                const float* __restrict__ Wout,
                const float* __restrict__ bout,
                float* __restrict__ out, int nsamp)
{
    __shared__ __align__(16) unsigned short hbuf[4][64 * 72];

    const int tid  = threadIdx.x;
    const int wid  = tid >> 6;
    const int lane = tid & 63;
    const int l15  = lane & 15;
    const int g    = lane >> 4;
    const int sbase = blockIdx.x * 256 + wid * 64;
    unsigned short* hw = hbuf[wid];

    bf16x8 b1hi[4], b1lo[4];
    float  b1v[4];
    #pragma unroll
    for (int n = 0; n < 4; ++n) {
        const float* wr = W1 + (n * 16 + l15) * 32 + g * 8;
        const f32x4 wv0 = ((const f4wrap*)wr)->v;
        const f32x4 wv1 = ((const f4wrap*)(wr + 4))->v;
        #pragma unroll
        for (int e = 0; e < 4; ++e) {
            split_bf(wv0[e], b1hi[n], b1lo[n], e);
            split_bf(wv1[e], b1hi[n], b1lo[n], e + 4);
        }
        b1v[n] = b1[n * 16 + l15];
    }

    // ---- layer 1: 4 M-tiles; A = 4 raw dwords (level g*4+d -> elems 2d,2d+1) ----
    #pragma unroll
    for (int m = 0; m < 4; ++m) {
        union { uint32_t u[4]; bf16x8 v; } af;
        const int s = sbase + m * 16 + l15;
        #pragma unroll
        for (int d = 0; d < 4; ++d)
            af.u[d] = enc_ws[(size_t)(g * 4 + d) * nsamp + s];
        #pragma unroll
        for (int n = 0; n < 4; ++n) {
            f32x4 acc = {0.f, 0.f, 0.f, 0.f};
            acc = __builtin_amdgcn_mfma_f32_16x16x32_bf16(af.v, b1lo[n], acc, 0, 0, 0);
            acc = __builtin_amdgcn_mfma_f32_16x16x32_bf16(af.v, b1hi[n], acc, 0, 0, 0);
            #pragma unroll
            for (int r = 0; r < 4; ++r) {
                const int row = m * 16 + g * 4 + r;
                const int col = n * 16 + l15;
                hw[row * 72 + col] = (unsigned short)f2bf(silu_f(acc[r] + b1v[n]));
            }
        }
    }

    // ---- layer 2: A = raw ds_read_b128 of 8 bf16; B2 split hi/lo ----
    f32x4 acc2[4][4];
    #pragma unroll
    for (int m = 0; m < 4; ++m)
        #pragma unroll
        for (int n = 0; n < 4; ++n)
            acc2[m][n] = f32x4{0.f, 0.f, 0.f, 0.f};

    #pragma unroll
    for (int ks = 0; ks < 2; ++ks) {
        bf16x8 b2hi[4], b2lo[4];
        #pragma unroll
        for (int n = 0; n < 4; ++n) {
            const float* wr = W2 + (n * 16 + l15) * 64 + ks * 32 + g * 8;
            const f32x4 wv0 = ((const f4wrap*)wr)->v;
            const f32x4 wv1 = ((const f4wrap*)(wr + 4))->v;
            #pragma unroll
            for (int e = 0; e < 4; ++e) {
                split_bf(wv0[e], b2hi[n], b2lo[n], e);
                split_bf(wv1[e], b2hi[n], b2lo[n], e + 4);
            }
        }
        #pragma unroll
        for (int m = 0; m < 4; ++m) {
            const bf16x8 a2 = *(const bf16x8*)&hw[(m * 16 + l15) * 72 + ks * 32 + g * 8];
            #pragma unroll
            for (int n = 0; n < 4; ++n) {
                acc2[m][n] = __builtin_amdgcn_mfma_f32_16x16x32_bf16(a2, b2lo[n], acc2[m][n], 0, 0, 0);
                acc2[m][n] = __builtin_amdgcn_mfma_f32_16x16x32_bf16(a2, b2hi[n], acc2[m][n], 0, 0, 0);
            }
        }
    }

    // ---- layer 3: out = bout + sum_j silu(h2[j]) * Wout[j] (fp32) ----
    float b2v[4], wov[4];
    #pragma unroll
    for (int n = 0; n < 4; ++n) {
        b2v[n] = b2[n * 16 + l15];
        wov[n] = Wout[n * 16 + l15];
    }
    const float bo = bout[0];

    #pragma unroll
    for (int m = 0; m < 4; ++m) {
        float part[4] = {0.f, 0.f, 0.f, 0.f};
        #pragma unroll
        for (int n = 0; n < 4; ++n)
            #pragma unroll
            for (int r = 0; r < 4; ++r)
                part[r] += silu_f(acc2[m][n][r] + b2v[n]) * wov[n];
        #pragma unroll
        for (int mask = 1; mask <= 8; mask <<= 1)
            #pragma unroll
            for (int r = 0; r < 4; ++r)
                part[r] += __shfl_xor(part[r], mask, 64);
        if (l15 == 0) {
            #pragma unroll
            for (int r = 0; r < 4; ++r)
                out[sbase + m * 16 + g * 4 + r] = part[r] + bo;
        }
    }
}

// ---------------- Fallback: monolithic (if ws too small) ----------------
__global__ void __launch_bounds__(BLOCK)
hashgrid_mlp_kernel(const float* __restrict__ x,
                    const float* __restrict__ emb,
                    const float* __restrict__ W1,
                    const float* __restrict__ b1,
                    const float* __restrict__ W2,
                    const float* __restrict__ b2,
                    const float* __restrict__ Wout,
                    const float* __restrict__ bout,
                    float* __restrict__ out,
                    ResArr res)
{
    const int t = threadIdx.x;
    const int s = blockIdx.x * BLOCK + t;

    const float xn0 = (x[(size_t)s * 3 + 0] + 1.0f) * 0.5f;
    const float xn1 = (x[(size_t)s * 3 + 1] + 1.0f) * 0.5f;
    const float xn2 = (x[(size_t)s * 3 + 2] + 1.0f) * 0.5f;

    float enc[2 * NLEV];
    #pragma unroll
    for (int l = 0; l < NLEV; ++l) {
        const float rs = res.r[l];
        const float g0 = xn0 * rs, g1 = xn1 * rs, g2 = xn2 * rs;
        const float f0 = floorf(g0), f1 = floorf(g1), f2 = floorf(g2);
        const float w0 = g0 - f0, w1 = g1 - f1, w2 = g2 - f2;
        const uint32_t hb = (uint32_t)f0 + (uint32_t)f1 * P1 + (uint32_t)f2 * P2;
        const float2* tab = (const float2*)emb + (size_t)l * TBL;
        const float om0 = 1.0f - w0, om1 = 1.0f - w1, om2 = 1.0f - w2;
        float e0 = 0.0f, e1 = 0.0f;
        #pragma unroll
        for (int c = 0; c < 8; ++c) {
            const uint32_t cb0 = (c >> 2) & 1, cb1 = (c >> 1) & 1, cb2 = c & 1;
            uint32_t h = hb;
            if (cb0) h += 1u;
            if (cb1) h += P1;
            if (cb2) h += P2;
            h &= TMASK;
            const float2 vv = tab[h];
            float wt = (cb0 ? w0 : om0) * (cb1 ? w1 : om1);
            wt *= (cb2 ? w2 : om2);
            e0 = fmaf(wt, vv.x, e0);
            e1 = fmaf(wt, vv.y, e1);
        }
        enc[2 * l + 0] = e0;
        enc[2 * l + 1] = e1;
    }

    float h1[64];
    #pragma unroll
    for (int i = 0; i < 64; ++i) {
        float acc = b1[i];
        #pragma unroll
        for (int k = 0; k < 32; ++k)
            acc = fmaf(enc[k], W1[i * 32 + k], acc);
        h1[i] = silu_f(acc);
    }
    float o = bout[0];
    #pragma unroll
    for (int i = 0; i < 64; ++i) {
        float acc = b2[i];
        #pragma unroll
        for (int k = 0; k < 64; ++k)
            acc = fmaf(h1[k], W2[i * 64 + k], acc);
        o = fmaf(silu_f(acc), Wout[i], o);
    }
    out[s] = o;
}

extern "C" void kernel_launch(void* const* d_in, const int* in_sizes, int n_in,
                              void* d_out, int out_size, void* d_ws, size_t ws_size,
                              hipStream_t stream) {
    const float* x    = (const float*)d_in[0];
    const float* emb  = (const float*)d_in[1];
    const float* W1   = (const float*)d_in[2];
    const float* b1   = (const float*)d_in[3];
    const float* W2   = (const float*)d_in[4];
    const float* b2   = (const float*)d_in[5];
    const float* Wout = (const float*)d_in[6];
    const float* bout = (const float*)d_in[7];
    float* out = (float*)d_out;

    ResArr res;
    const double lg0 = log(16.0), lg1 = log(2048.0);
    for (int i = 0; i < NLEV; ++i)
        res.r[i] = (float)exp(lg0 + (lg1 - lg0) * (double)i / 15.0);

    const int n = in_sizes[0] / 3;                     // 262144 samples
    const size_t ws_needed = (size_t)n * NLEV * sizeof(uint32_t);

    if (ws_size >= ws_needed) {
        uint32_t* enc_ws = (uint32_t*)d_ws;
        dim3 gridA(4096);                              // 512 blocks per XCD, balanced
        encode_kernel<<<gridA, BLOCK, 0, stream>>>(x, emb, enc_ws, n, res);
        dim3 gridB(n / 256);                           // 1024 blocks, 256 samples each
        mlp_mfma_kernel<<<gridB, BLOCK, 0, stream>>>(enc_ws, W1, b1, W2, b2,
                                                     Wout, bout, out, n);
    } else {
        dim3 grid(n / BLOCK);
        hashgrid_mlp_kernel<<<grid, BLOCK, 0, stream>>>(x, emb, W1, b1, W2, b2,
                                                        Wout, bout, out, res);
    }
}